// Round 1
// baseline (555.988 us; speedup 1.0000x reference)
//
#include <hip/hip_runtime.h>

#define NB 8
#define NN 2048
#define NM 8192
#define NC 64
#define ND 64
#define NK 16

// ---------------------------------------------------------------------------
// Kernel 1: feats = transpose(features), x = feats @ W1^T + b1
// grid (NN/64, NB), block 256. One block handles 64 n-values of one batch.
// ---------------------------------------------------------------------------
__global__ __launch_bounds__(256) void feats_linear_kernel(
    const float* __restrict__ features, const float* __restrict__ W1,
    const float* __restrict__ b1, float* __restrict__ out_feats,
    float* __restrict__ out_x) {
  // row stride 68 floats: 272B rows -> 16B aligned for float4 reads,
  // bank = (4c + j) % 32 (acceptable; phases using it are tiny)
  __shared__ float tile[NC][68];   // tile[c][n_local] = features[b][c][n0+n_local]
  __shared__ float Wt[NC][68];     // Wt[c][d] = W1[d][c]

  const int b = blockIdx.y;
  const int n0 = blockIdx.x * 64;
  const int t = threadIdx.x;
  const int lane = t & 63;
  const int grp = t >> 6;  // 0..3, wave-uniform

  // load features tile (coalesced along n)
  for (int c = grp; c < NC; c += 4)
    tile[c][lane] = features[((size_t)(b * NC + c) * NN) + n0 + lane];
  // load W1 transposed into LDS
  for (int i = t; i < NC * ND; i += 256) {
    const int d = i >> 6, c = i & 63;
    Wt[c][d] = W1[i];
  }
  __syncthreads();

  // feats[b][n][c] = tile[c][n_local]; lanes along c -> coalesced stores
  for (int j = grp; j < 64; j += 4)
    out_feats[((size_t)(b * NN + n0 + j) * NC) + lane] = tile[lane][j];

  // x[b][n][d] = b1[d] + sum_c tile[c][n]*Wt[c][d]
  const int d = lane;
  float acc[16];
  const float bd = b1[d];
#pragma unroll
  for (int jj = 0; jj < 16; jj++) acc[jj] = bd;

  const float4* tv = (const float4*)&tile[0][0];  // 17 float4 per row
  for (int c = 0; c < NC; c++) {
    const float w = Wt[c][d];  // lanes d consecutive: conflict-free
#pragma unroll
    for (int q = 0; q < 4; q++) {
      const float4 v = tv[c * 17 + grp * 4 + q];  // wave-uniform broadcast
      acc[q * 4 + 0] = fmaf(v.x, w, acc[q * 4 + 0]);
      acc[q * 4 + 1] = fmaf(v.y, w, acc[q * 4 + 1]);
      acc[q * 4 + 2] = fmaf(v.z, w, acc[q * 4 + 2]);
      acc[q * 4 + 3] = fmaf(v.w, w, acc[q * 4 + 3]);
    }
  }
#pragma unroll
  for (int jj = 0; jj < 16; jj++) {
    const int j = grp * 16 + jj;
    out_x[((size_t)(b * NN + n0 + j) * ND) + d] = acc[jj];  // coalesced in d
  }
}

// ---------------------------------------------------------------------------
// Kernel 2: exact stable kNN (k=16) + gather.
// grid (NM/256, NB), block 256, thread = one query.
// d2 computed bit-identically to numpy: rn sub/mul, sum order (x+y)+z, no fma.
// ---------------------------------------------------------------------------
__global__ __launch_bounds__(256) void knn_kernel(
    const float* __restrict__ xyz, const float* __restrict__ xyz_fp,
    float* __restrict__ out_knn) {
  __shared__ float4 pts[NN];                 // 32 KB point cache
  __shared__ unsigned short cidx[32][256];   // 16 KB candidate indices

  const int b = blockIdx.y;
  const int t = threadIdx.x;

  const float* P = xyz + (size_t)b * NN * 3;
  for (int i = t; i < NN; i += 256)
    pts[i] = make_float4(P[3 * i + 0], P[3 * i + 1], P[3 * i + 2], 0.0f);
  __syncthreads();

  const int m = blockIdx.x * 256 + t;
  const float* Q = xyz_fp + ((size_t)b * NM + m) * 3;
  const float qx = Q[0], qy = Q[1], qz = Q[2];

  // ---- pass 1: exact 16th-smallest distance via branchless min/max chain ----
  float s[NK];
#pragma unroll
  for (int j = 0; j < NK; j++) s[j] = 3.0e38f;

  for (int i = 0; i < NN; i++) {
    const float4 p = pts[i];
    const float dx = __fsub_rn(qx, p.x);
    const float dy = __fsub_rn(qy, p.y);
    const float dz = __fsub_rn(qz, p.z);
    const float d2 = __fadd_rn(
        __fadd_rn(__fmul_rn(dx, dx), __fmul_rn(dy, dy)), __fmul_rn(dz, dz));
    if (d2 < s[NK - 1]) {
      float v = d2;
#pragma unroll
      for (int j = 0; j < NK; j++) {
        const float lo = fminf(v, s[j]);
        const float hi = fmaxf(v, s[j]);
        s[j] = lo;
        v = hi;
      }
    }
  }
  const float T = s[NK - 1];  // exact 16th order statistic (with multiplicity)

  // ---- pass 2: collect all candidates with d2 <= T (>=16, ~16 expected) ----
  int cnt = 0;
  for (int i = 0; i < NN; i++) {
    const float4 p = pts[i];
    const float dx = __fsub_rn(qx, p.x);
    const float dy = __fsub_rn(qy, p.y);
    const float dz = __fsub_rn(qz, p.z);
    const float d2 = __fadd_rn(
        __fadd_rn(__fmul_rn(dx, dx), __fmul_rn(dy, dy)), __fmul_rn(dz, dz));
    if (d2 <= T) {
      if (cnt < 32) cidx[cnt][t] = (unsigned short)i;
      cnt++;
    }
  }
  if (cnt > 32) cnt = 32;

  // ---- final: stable top-16 by (d2, idx) lexicographic u64 keys ----
  unsigned long long kb[NK];
#pragma unroll
  for (int j = 0; j < NK; j++) kb[j] = ~0ULL;

  for (int c = 0; c < cnt; c++) {
    const int i = cidx[c][t];
    const float4 p = pts[i];
    const float dx = __fsub_rn(qx, p.x);
    const float dy = __fsub_rn(qy, p.y);
    const float dz = __fsub_rn(qz, p.z);
    const float d2 = __fadd_rn(
        __fadd_rn(__fmul_rn(dx, dx), __fmul_rn(dy, dy)), __fmul_rn(dz, dz));
    // d2 >= 0 -> float bit pattern is order-preserving as u32
    unsigned long long kk =
        ((unsigned long long)__float_as_uint(d2) << 32) | (unsigned)i;
    if (kk < kb[NK - 1]) {
#pragma unroll
      for (int j = 0; j < NK; j++) {
        const bool c2 = kk < kb[j];
        const unsigned long long lo = c2 ? kk : kb[j];
        const unsigned long long hi = c2 ? kb[j] : kk;
        kb[j] = lo;
        kk = hi;
      }
    }
  }

  // ---- gather + write ----
  float* o = out_knn + (size_t)(b * NM + m) * (NK * 3);
#pragma unroll
  for (int j = 0; j < NK; j++) {
    const float4 p = pts[(unsigned)kb[j]];  // low 32 bits = point index
    o[3 * j + 0] = p.x;
    o[3 * j + 1] = p.y;
    o[3 * j + 2] = p.z;
  }
}

// ---------------------------------------------------------------------------
extern "C" void kernel_launch(void* const* d_in, const int* in_sizes, int n_in,
                              void* d_out, int out_size, void* d_ws,
                              size_t ws_size, hipStream_t stream) {
  const float* xyz      = (const float*)d_in[0];  // [8,2048,3]
  const float* xyz_fp   = (const float*)d_in[1];  // [8,8192,3]
  const float* features = (const float*)d_in[2];  // [8,64,2048]
  // d_in[3] = features_fp: unused by reference outputs
  const float* W1 = (const float*)d_in[4];        // [64,64]
  const float* b1 = (const float*)d_in[5];        // [64]
  // d_in[6] = k (==16), hardcoded

  float* out_feats = (float*)d_out;                          // 8*2048*64
  float* out_knn   = out_feats + (size_t)NB * NN * NC;       // 8*8192*16*3
  float* out_x     = out_knn + (size_t)NB * NM * NK * 3;     // 8*2048*64

  feats_linear_kernel<<<dim3(NN / 64, NB), 256, 0, stream>>>(
      features, W1, b1, out_feats, out_x);
  knn_kernel<<<dim3(NM / 256, NB), 256, 0, stream>>>(xyz, xyz_fp, out_knn);
}

// Round 2
// 236.035 us; speedup vs baseline: 2.3555x; 2.3555x over previous
//
#include <hip/hip_runtime.h>

#define NB 8
#define NN 2048
#define NM 8192
#define NC 64
#define ND 64
#define NK 16

#define PARTS 4
#define PPT 512      // points per thread (NN / PARTS)
#define CHUNK 516    // padded chunk stride in floats (512 + 4 -> bank offset 4)
#define QPB 64       // queries per block (256 threads / 4 parts)
#define CAP 24       // candidate slots per query

// ---------------------------------------------------------------------------
// Kernel 1: feats = transpose(features), x = feats @ W1^T + b1  (unchanged)
// ---------------------------------------------------------------------------
__global__ __launch_bounds__(256) void feats_linear_kernel(
    const float* __restrict__ features, const float* __restrict__ W1,
    const float* __restrict__ b1, float* __restrict__ out_feats,
    float* __restrict__ out_x) {
  __shared__ float tile[NC][68];
  __shared__ float Wt[NC][68];

  const int b = blockIdx.y;
  const int n0 = blockIdx.x * 64;
  const int t = threadIdx.x;
  const int lane = t & 63;
  const int grp = t >> 6;

  for (int c = grp; c < NC; c += 4)
    tile[c][lane] = features[((size_t)(b * NC + c) * NN) + n0 + lane];
  for (int i = t; i < NC * ND; i += 256) {
    const int d = i >> 6, c = i & 63;
    Wt[c][d] = W1[i];
  }
  __syncthreads();

  for (int j = grp; j < 64; j += 4)
    out_feats[((size_t)(b * NN + n0 + j) * NC) + lane] = tile[lane][j];

  const int d = lane;
  float acc[16];
  const float bd = b1[d];
#pragma unroll
  for (int jj = 0; jj < 16; jj++) acc[jj] = bd;

  const float4* tv = (const float4*)&tile[0][0];
  for (int c = 0; c < NC; c++) {
    const float w = Wt[c][d];
#pragma unroll
    for (int q = 0; q < 4; q++) {
      const float4 v = tv[c * 17 + grp * 4 + q];
      acc[q * 4 + 0] = fmaf(v.x, w, acc[q * 4 + 0]);
      acc[q * 4 + 1] = fmaf(v.y, w, acc[q * 4 + 1]);
      acc[q * 4 + 2] = fmaf(v.z, w, acc[q * 4 + 2]);
      acc[q * 4 + 3] = fmaf(v.w, w, acc[q * 4 + 3]);
    }
  }
#pragma unroll
  for (int jj = 0; jj < 16; jj++) {
    const int j = grp * 16 + jj;
    out_x[((size_t)(b * NN + n0 + j) * ND) + d] = acc[jj];
  }
}

// ---------------------------------------------------------------------------
// Kernel 2: exact stable kNN, 4 threads per query, batch-8 network inserts.
// ---------------------------------------------------------------------------
__device__ __forceinline__ float d2rn(float qx, float qy, float qz, float x,
                                      float y, float z) {
  const float dx = __fsub_rn(qx, x);
  const float dy = __fsub_rn(qy, y);
  const float dz = __fsub_rn(qz, z);
  return __fadd_rn(__fadd_rn(__fmul_rn(dx, dx), __fmul_rn(dy, dy)),
                   __fmul_rn(dz, dz));
}

// compare-exchange on array a
#define CE(a, i, j)                     \
  {                                     \
    const float lo = fminf(a[i], a[j]); \
    const float hi = fmaxf(a[i], a[j]); \
    a[i] = lo;                          \
    a[j] = hi;                          \
  }

// Batcher odd-even sort of d[8] ascending (19 comparators)
#define SORT8(d)                                  \
  CE(d, 0, 1) CE(d, 2, 3) CE(d, 4, 5) CE(d, 6, 7) \
  CE(d, 0, 2) CE(d, 1, 3) CE(d, 4, 6) CE(d, 5, 7) \
  CE(d, 1, 2) CE(d, 5, 6)                         \
  CE(d, 0, 4) CE(d, 1, 5) CE(d, 2, 6) CE(d, 3, 7) \
  CE(d, 2, 4) CE(d, 3, 5)                         \
  CE(d, 1, 2) CE(d, 3, 4) CE(d, 5, 6)

// bitonic sort of L[16] (input bitonic) ascending: 32 comparators
#define BITONIC16(L)                                                      \
  CE(L, 0, 8) CE(L, 1, 9) CE(L, 2, 10) CE(L, 3, 11) CE(L, 4, 12)          \
  CE(L, 5, 13) CE(L, 6, 14) CE(L, 7, 15)                                  \
  CE(L, 0, 4) CE(L, 1, 5) CE(L, 2, 6) CE(L, 3, 7) CE(L, 8, 12)            \
  CE(L, 9, 13) CE(L, 10, 14) CE(L, 11, 15)                                \
  CE(L, 0, 2) CE(L, 1, 3) CE(L, 4, 6) CE(L, 5, 7) CE(L, 8, 10)            \
  CE(L, 9, 11) CE(L, 12, 14) CE(L, 13, 15)                                \
  CE(L, 0, 1) CE(L, 2, 3) CE(L, 4, 5) CE(L, 6, 7) CE(L, 8, 9)             \
  CE(L, 10, 11) CE(L, 12, 13) CE(L, 14, 15)

__global__ __launch_bounds__(256, 4) void knn_kernel(
    const float* __restrict__ xyz, const float* __restrict__ xyz_fp,
    float* __restrict__ out_knn) {
  __shared__ __align__(16) float px[PARTS * CHUNK];
  __shared__ __align__(16) float py[PARTS * CHUNK];
  __shared__ __align__(16) float pz[PARTS * CHUNK];
  __shared__ int cand[QPB * CAP];
  __shared__ int ccnt[QPB];

  const int b = blockIdx.y;
  const int t = threadIdx.x;
  const int qlocal = t >> 2;  // 0..63
  const int part = t & 3;     // 0..3  (low bits -> same wave for a query)

  if (t < QPB) ccnt[t] = 0;

  // stage points SoA, part-chunked with +4 float pad per chunk
  const float* P = xyz + (size_t)b * NN * 3;
  for (int i = t; i < NN; i += 256) {
    const int slot = (i >> 9) * CHUNK + (i & 511);
    px[slot] = P[3 * i + 0];
    py[slot] = P[3 * i + 1];
    pz[slot] = P[3 * i + 2];
  }
  __syncthreads();

  const int q = blockIdx.x * QPB + qlocal;
  const float* Q = xyz_fp + ((size_t)b * NM + q) * 3;
  const float qx = Q[0], qy = Q[1], qz = Q[2];

  const int base = part * CHUNK;

  // ---- pass 1: local sorted top-16 distances over my 512 points ----
  float s[16];
#pragma unroll
  for (int j = 0; j < 16; j++) s[j] = 3.0e38f;

  for (int i0 = 0; i0 < PPT; i0 += 8) {
    const float4 X0 = *(const float4*)&px[base + i0];
    const float4 X1 = *(const float4*)&px[base + i0 + 4];
    const float4 Y0 = *(const float4*)&py[base + i0];
    const float4 Y1 = *(const float4*)&py[base + i0 + 4];
    const float4 Z0 = *(const float4*)&pz[base + i0];
    const float4 Z1 = *(const float4*)&pz[base + i0 + 4];
    float d[8];
    d[0] = d2rn(qx, qy, qz, X0.x, Y0.x, Z0.x);
    d[1] = d2rn(qx, qy, qz, X0.y, Y0.y, Z0.y);
    d[2] = d2rn(qx, qy, qz, X0.z, Y0.z, Z0.z);
    d[3] = d2rn(qx, qy, qz, X0.w, Y0.w, Z0.w);
    d[4] = d2rn(qx, qy, qz, X1.x, Y1.x, Z1.x);
    d[5] = d2rn(qx, qy, qz, X1.y, Y1.y, Z1.y);
    d[6] = d2rn(qx, qy, qz, X1.z, Y1.z, Z1.z);
    d[7] = d2rn(qx, qy, qz, X1.w, Y1.w, Z1.w);
    SORT8(d)
    // keep lowest 16 of s[16] ∪ d[8]: tail fold (d reversed) then bitonic sort
    float L[16];
#pragma unroll
    for (int j = 0; j < 8; j++) L[j] = s[j];
#pragma unroll
    for (int j = 0; j < 8; j++) L[8 + j] = fminf(s[8 + j], d[7 - j]);
    BITONIC16(L)
#pragma unroll
    for (int j = 0; j < 16; j++) s[j] = L[j];
  }

  // ---- butterfly merge across the 4 parts: all lanes get global top-16 ----
#pragma unroll
  for (int mask = 1; mask <= 2; mask <<= 1) {
    float B[16];
#pragma unroll
    for (int j = 0; j < 16; j++) B[j] = __shfl_xor(s[j], mask, 64);
    float L[16];
#pragma unroll
    for (int j = 0; j < 16; j++) L[j] = fminf(s[j], B[15 - j]);
    BITONIC16(L)
#pragma unroll
    for (int j = 0; j < 16; j++) s[j] = L[j];
  }
  const float T = s[15];  // exact 16th-smallest d2 (multiset) for query q

  // ---- pass 2: collect candidates with d2 <= T from my 512 points ----
  const int gbase = part * PPT;
  for (int i0 = 0; i0 < PPT; i0 += 8) {
    const float4 X0 = *(const float4*)&px[base + i0];
    const float4 X1 = *(const float4*)&px[base + i0 + 4];
    const float4 Y0 = *(const float4*)&py[base + i0];
    const float4 Y1 = *(const float4*)&py[base + i0 + 4];
    const float4 Z0 = *(const float4*)&pz[base + i0];
    const float4 Z1 = *(const float4*)&pz[base + i0 + 4];
    float d[8];
    d[0] = d2rn(qx, qy, qz, X0.x, Y0.x, Z0.x);
    d[1] = d2rn(qx, qy, qz, X0.y, Y0.y, Z0.y);
    d[2] = d2rn(qx, qy, qz, X0.z, Y0.z, Z0.z);
    d[3] = d2rn(qx, qy, qz, X0.w, Y0.w, Z0.w);
    d[4] = d2rn(qx, qy, qz, X1.x, Y1.x, Z1.x);
    d[5] = d2rn(qx, qy, qz, X1.y, Y1.y, Z1.y);
    d[6] = d2rn(qx, qy, qz, X1.z, Y1.z, Z1.z);
    d[7] = d2rn(qx, qy, qz, X1.w, Y1.w, Z1.w);
    float m = fminf(fminf(fminf(d[0], d[1]), fminf(d[2], d[3])),
                    fminf(fminf(d[4], d[5]), fminf(d[6], d[7])));
    if (m <= T) {
#pragma unroll
      for (int j = 0; j < 8; j++) {
        if (d[j] <= T) {
          const int pos = atomicAdd(&ccnt[qlocal], 1);
          if (pos < CAP) cand[qlocal * CAP + pos] = gbase + i0 + j;
        }
      }
    }
  }
  __syncthreads();

  // ---- phase 3: stable top-16 by (d2, idx) u64 keys (one lane per query) ----
  if (part == 0) {
    int n = ccnt[qlocal];
    if (n > CAP) n = CAP;
    unsigned long long kb[NK];
#pragma unroll
    for (int j = 0; j < NK; j++) kb[j] = ~0ULL;
    for (int c = 0; c < n; c++) {
      const int i = cand[qlocal * CAP + c];
      const int slot = (i >> 9) * CHUNK + (i & 511);
      const float d2 = d2rn(qx, qy, qz, px[slot], py[slot], pz[slot]);
      unsigned long long kk =
          ((unsigned long long)__float_as_uint(d2) << 32) | (unsigned)i;
      if (kk < kb[NK - 1]) {
#pragma unroll
        for (int j = 0; j < NK; j++) {
          const bool c2 = kk < kb[j];
          const unsigned long long lo = c2 ? kk : kb[j];
          const unsigned long long hi = c2 ? kb[j] : kk;
          kb[j] = lo;
          kk = hi;
        }
      }
    }
#pragma unroll
    for (int j = 0; j < NK; j++)
      cand[qlocal * CAP + j] = (int)(unsigned)kb[j];  // stable idx order
  }
  __syncthreads();

  // ---- output: each part lane writes 4 neighbors (12 floats) ----
  float* o = out_knn + ((size_t)(b * NM + q)) * (NK * 3);
#pragma unroll
  for (int jj = 0; jj < 4; jj++) {
    const int j = part * 4 + jj;
    const int i = cand[qlocal * CAP + j];
    const int slot = (i >> 9) * CHUNK + (i & 511);
    o[3 * j + 0] = px[slot];
    o[3 * j + 1] = py[slot];
    o[3 * j + 2] = pz[slot];
  }
}

// ---------------------------------------------------------------------------
extern "C" void kernel_launch(void* const* d_in, const int* in_sizes, int n_in,
                              void* d_out, int out_size, void* d_ws,
                              size_t ws_size, hipStream_t stream) {
  const float* xyz      = (const float*)d_in[0];  // [8,2048,3]
  const float* xyz_fp   = (const float*)d_in[1];  // [8,8192,3]
  const float* features = (const float*)d_in[2];  // [8,64,2048]
  const float* W1 = (const float*)d_in[4];        // [64,64]
  const float* b1 = (const float*)d_in[5];        // [64]

  float* out_feats = (float*)d_out;                       // 8*2048*64
  float* out_knn   = out_feats + (size_t)NB * NN * NC;    // 8*8192*16*3
  float* out_x     = out_knn + (size_t)NB * NM * NK * 3;  // 8*2048*64

  feats_linear_kernel<<<dim3(NN / 64, NB), 256, 0, stream>>>(
      features, W1, b1, out_feats, out_x);
  knn_kernel<<<dim3(NM / QPB, NB), 256, 0, stream>>>(xyz, xyz_fp, out_knn);
}

// Round 3
// 199.888 us; speedup vs baseline: 2.7815x; 1.1808x over previous
//
#include <hip/hip_runtime.h>

#define NB 8
#define NN 2048
#define NM 8192
#define NC 64
#define ND 64
#define NK 16

#define PARTS 8     // lanes per query
#define PPT 256     // points per lane (NN / PARTS)
#define CHUNK 260   // padded chunk stride in floats: 260%32==4 -> parts on
                    // distinct bank-quads -> conflict-free ds_read_b128
#define QPB 32      // queries per block (256 threads / 8 parts)
#define NG 8        // groups of 32 points per lane
#define CAP 64      // candidate slots per query (overflow prob ~e^-40 + exact fallback)

// ---------------------------------------------------------------------------
// Kernel 1: feats = transpose(features), x = feats @ W1^T + b1  (unchanged)
// ---------------------------------------------------------------------------
__global__ __launch_bounds__(256) void feats_linear_kernel(
    const float* __restrict__ features, const float* __restrict__ W1,
    const float* __restrict__ b1, float* __restrict__ out_feats,
    float* __restrict__ out_x) {
  __shared__ float tile[NC][68];
  __shared__ float Wt[NC][68];

  const int b = blockIdx.y;
  const int n0 = blockIdx.x * 64;
  const int t = threadIdx.x;
  const int lane = t & 63;
  const int grp = t >> 6;

  for (int c = grp; c < NC; c += 4)
    tile[c][lane] = features[((size_t)(b * NC + c) * NN) + n0 + lane];
  for (int i = t; i < NC * ND; i += 256) {
    const int d = i >> 6, c = i & 63;
    Wt[c][d] = W1[i];
  }
  __syncthreads();

  for (int j = grp; j < 64; j += 4)
    out_feats[((size_t)(b * NN + n0 + j) * NC) + lane] = tile[lane][j];

  const int d = lane;
  float acc[16];
  const float bd = b1[d];
#pragma unroll
  for (int jj = 0; jj < 16; jj++) acc[jj] = bd;

  const float4* tv = (const float4*)&tile[0][0];
  for (int c = 0; c < NC; c++) {
    const float w = Wt[c][d];
#pragma unroll
    for (int q = 0; q < 4; q++) {
      const float4 v = tv[c * 17 + grp * 4 + q];
      acc[q * 4 + 0] = fmaf(v.x, w, acc[q * 4 + 0]);
      acc[q * 4 + 1] = fmaf(v.y, w, acc[q * 4 + 1]);
      acc[q * 4 + 2] = fmaf(v.z, w, acc[q * 4 + 2]);
      acc[q * 4 + 3] = fmaf(v.w, w, acc[q * 4 + 3]);
    }
  }
#pragma unroll
  for (int jj = 0; jj < 16; jj++) {
    const int j = grp * 16 + jj;
    out_x[((size_t)(b * NN + n0 + j) * ND) + d] = acc[jj];
  }
}

// ---------------------------------------------------------------------------
// Kernel 2: exact stable kNN via group-min threshold bound.
// ---------------------------------------------------------------------------
__device__ __forceinline__ float d2rn(float qx, float qy, float qz, float x,
                                      float y, float z) {
  const float dx = __fsub_rn(qx, x);
  const float dy = __fsub_rn(qy, y);
  const float dz = __fsub_rn(qz, z);
  return __fadd_rn(__fadd_rn(__fmul_rn(dx, dx), __fmul_rn(dy, dy)),
                   __fmul_rn(dz, dz));
}

#define CE(a, i, j)                     \
  {                                     \
    const float lo = fminf(a[i], a[j]); \
    const float hi = fmaxf(a[i], a[j]); \
    a[i] = lo;                          \
    a[j] = hi;                          \
  }

// Batcher odd-even sort of d[8] ascending (19 comparators)
#define SORT8(d)                                  \
  CE(d, 0, 1) CE(d, 2, 3) CE(d, 4, 5) CE(d, 6, 7) \
  CE(d, 0, 2) CE(d, 1, 3) CE(d, 4, 6) CE(d, 5, 7) \
  CE(d, 1, 2) CE(d, 5, 6)                         \
  CE(d, 0, 4) CE(d, 1, 5) CE(d, 2, 6) CE(d, 3, 7) \
  CE(d, 2, 4) CE(d, 3, 5)                         \
  CE(d, 1, 2) CE(d, 3, 4) CE(d, 5, 6)

// bitonic sort of L[16] (input bitonic) ascending: 32 comparators
#define BITONIC16(L)                                                      \
  CE(L, 0, 8) CE(L, 1, 9) CE(L, 2, 10) CE(L, 3, 11) CE(L, 4, 12)          \
  CE(L, 5, 13) CE(L, 6, 14) CE(L, 7, 15)                                  \
  CE(L, 0, 4) CE(L, 1, 5) CE(L, 2, 6) CE(L, 3, 7) CE(L, 8, 12)            \
  CE(L, 9, 13) CE(L, 10, 14) CE(L, 11, 15)                                \
  CE(L, 0, 2) CE(L, 1, 3) CE(L, 4, 6) CE(L, 5, 7) CE(L, 8, 10)            \
  CE(L, 9, 11) CE(L, 12, 14) CE(L, 13, 15)                                \
  CE(L, 0, 1) CE(L, 2, 3) CE(L, 4, 5) CE(L, 6, 7) CE(L, 8, 9)             \
  CE(L, 10, 11) CE(L, 12, 13) CE(L, 14, 15)

__device__ __forceinline__ void dist8(const float* px, const float* py,
                                      const float* pz, int base, float qx,
                                      float qy, float qz, float d[8]) {
  const float4 X0 = *(const float4*)&px[base];
  const float4 X1 = *(const float4*)&px[base + 4];
  const float4 Y0 = *(const float4*)&py[base];
  const float4 Y1 = *(const float4*)&py[base + 4];
  const float4 Z0 = *(const float4*)&pz[base];
  const float4 Z1 = *(const float4*)&pz[base + 4];
  d[0] = d2rn(qx, qy, qz, X0.x, Y0.x, Z0.x);
  d[1] = d2rn(qx, qy, qz, X0.y, Y0.y, Z0.y);
  d[2] = d2rn(qx, qy, qz, X0.z, Y0.z, Z0.z);
  d[3] = d2rn(qx, qy, qz, X0.w, Y0.w, Z0.w);
  d[4] = d2rn(qx, qy, qz, X1.x, Y1.x, Z1.x);
  d[5] = d2rn(qx, qy, qz, X1.y, Y1.y, Z1.y);
  d[6] = d2rn(qx, qy, qz, X1.z, Y1.z, Z1.z);
  d[7] = d2rn(qx, qy, qz, X1.w, Y1.w, Z1.w);
}

__device__ __forceinline__ float min8(const float d[8]) {
  return fminf(fminf(fminf(d[0], d[1]), fminf(d[2], d[3])),
               fminf(fminf(d[4], d[5]), fminf(d[6], d[7])));
}

__global__ __launch_bounds__(256, 4) void knn_kernel(
    const float* __restrict__ xyz, const float* __restrict__ xyz_fp,
    float* __restrict__ out_knn) {
  __shared__ __align__(16) float px[PARTS * CHUNK];
  __shared__ __align__(16) float py[PARTS * CHUNK];
  __shared__ __align__(16) float pz[PARTS * CHUNK];
  __shared__ unsigned short cand[QPB * CAP];
  __shared__ int ccnt[QPB];

  const int b = blockIdx.y;
  const int t = threadIdx.x;
  const int ql = t >> 3;   // query-local 0..31
  const int part = t & 7;  // 0..7

  if (t < QPB) ccnt[t] = 0;

  // stage points SoA, chunked per part with +4 float pad
  const float* P = xyz + (size_t)b * NN * 3;
  for (int i = t; i < NN; i += 256) {
    const int slot = (i >> 8) * CHUNK + (i & 255);
    px[slot] = P[3 * i + 0];
    py[slot] = P[3 * i + 1];
    pz[slot] = P[3 * i + 2];
  }
  __syncthreads();

  const int q = blockIdx.x * QPB + ql;
  const float* Q = xyz_fp + ((size_t)b * NM + q) * 3;
  const float qx = Q[0], qy = Q[1], qz = Q[2];

  const int pbase = part * CHUNK;

  // ---- pass 1: group mins (8 groups of 32 points per lane) ----
  float gmin[NG];
#pragma unroll
  for (int g = 0; g < NG; g++) {
    float gm = 3.0e38f;
#pragma unroll
    for (int bb = 0; bb < 4; bb++) {
      float d[8];
      dist8(px, py, pz, pbase + g * 32 + bb * 8, qx, qy, qz, d);
      gm = fminf(gm, min8(d));
    }
    gmin[g] = gm;
  }

  // ---- T = 16th-smallest of the query's 64 group-mins (upper bound on
  //      the exact 16th-smallest distance; each gmin is a distinct point) ----
  float s[16];
  {
    float g8[NG];
#pragma unroll
    for (int g = 0; g < NG; g++) g8[g] = gmin[g];
    SORT8(g8)
#pragma unroll
    for (int j = 0; j < 8; j++) s[j] = g8[j];
#pragma unroll
    for (int j = 8; j < 16; j++) s[j] = 3.0e38f;
  }
#pragma unroll
  for (int mask = 1; mask <= 4; mask <<= 1) {
    float B[16];
#pragma unroll
    for (int j = 0; j < 16; j++) B[j] = __shfl_xor(s[j], mask, 64);
    float L[16];
#pragma unroll
    for (int j = 0; j < 16; j++) L[j] = fminf(s[j], B[15 - j]);
    BITONIC16(L)
#pragma unroll
    for (int j = 0; j < 16; j++) s[j] = L[j];
  }
  const float T = s[15];

  // ---- pass 2: scan only groups with gmin <= T, collect candidates ----
  int gm_mask = 0;
#pragma unroll
  for (int g = 0; g < NG; g++) gm_mask |= (gmin[g] <= T) ? (1 << g) : 0;

  while (gm_mask) {
    const int g = __ffs(gm_mask) - 1;
    gm_mask &= gm_mask - 1;
    const int gb = pbase + g * 32;
#pragma unroll
    for (int bb = 0; bb < 4; bb++) {
      float d[8];
      dist8(px, py, pz, gb + bb * 8, qx, qy, qz, d);
      if (min8(d) <= T) {
#pragma unroll
        for (int j = 0; j < 8; j++) {
          if (d[j] <= T) {
            const int pos = atomicAdd(&ccnt[ql], 1);
            if (pos < CAP)
              cand[ql * CAP + pos] =
                  (unsigned short)(part * PPT + g * 32 + bb * 8 + j);
          }
        }
      }
    }
  }
  __syncthreads();

  // ---- phase 3: exact stable top-16 by (d2, idx) u64 keys ----
  if (part == 0) {
    const int cnt = ccnt[ql];
    unsigned long long kb[NK];
#pragma unroll
    for (int j = 0; j < NK; j++) kb[j] = ~0ULL;

    if (cnt <= CAP) {
      for (int c = 0; c < cnt; c++) {
        const int i = cand[ql * CAP + c];
        const int slot = (i >> 8) * CHUNK + (i & 255);
        const float d2 = d2rn(qx, qy, qz, px[slot], py[slot], pz[slot]);
        unsigned long long kk =
            ((unsigned long long)__float_as_uint(d2) << 32) | (unsigned)i;
        if (kk < kb[NK - 1]) {
#pragma unroll
          for (int j = 0; j < NK; j++) {
            const bool c2 = kk < kb[j];
            const unsigned long long lo = c2 ? kk : kb[j];
            const unsigned long long hi = c2 ? kb[j] : kk;
            kb[j] = lo;
            kk = hi;
          }
        }
      }
    } else {
      // overflow fallback (astronomically rare): exact scan of all points
      for (int i = 0; i < NN; i++) {
        const int slot = (i >> 8) * CHUNK + (i & 255);
        const float d2 = d2rn(qx, qy, qz, px[slot], py[slot], pz[slot]);
        unsigned long long kk =
            ((unsigned long long)__float_as_uint(d2) << 32) | (unsigned)i;
        if (kk < kb[NK - 1]) {
#pragma unroll
          for (int j = 0; j < NK; j++) {
            const bool c2 = kk < kb[j];
            const unsigned long long lo = c2 ? kk : kb[j];
            const unsigned long long hi = c2 ? kb[j] : kk;
            kb[j] = lo;
            kk = hi;
          }
        }
      }
    }
#pragma unroll
    for (int j = 0; j < NK; j++)
      cand[ql * CAP + j] = (unsigned short)(unsigned)kb[j];
  }
  __syncthreads();

  // ---- output: each part lane writes 2 neighbors (6 floats) ----
  float* o = out_knn + ((size_t)(b * NM + q)) * (NK * 3);
#pragma unroll
  for (int jj = 0; jj < 2; jj++) {
    const int j = part * 2 + jj;
    const int i = cand[ql * CAP + j];
    const int slot = (i >> 8) * CHUNK + (i & 255);
    o[3 * j + 0] = px[slot];
    o[3 * j + 1] = py[slot];
    o[3 * j + 2] = pz[slot];
  }
}

// ---------------------------------------------------------------------------
extern "C" void kernel_launch(void* const* d_in, const int* in_sizes, int n_in,
                              void* d_out, int out_size, void* d_ws,
                              size_t ws_size, hipStream_t stream) {
  const float* xyz      = (const float*)d_in[0];  // [8,2048,3]
  const float* xyz_fp   = (const float*)d_in[1];  // [8,8192,3]
  const float* features = (const float*)d_in[2];  // [8,64,2048]
  const float* W1 = (const float*)d_in[4];        // [64,64]
  const float* b1 = (const float*)d_in[5];        // [64]

  float* out_feats = (float*)d_out;                       // 8*2048*64
  float* out_knn   = out_feats + (size_t)NB * NN * NC;    // 8*8192*16*3
  float* out_x     = out_knn + (size_t)NB * NM * NK * 3;  // 8*2048*64

  feats_linear_kernel<<<dim3(NN / 64, NB), 256, 0, stream>>>(
      features, W1, b1, out_feats, out_x);
  knn_kernel<<<dim3(NM / QPB, NB), 256, 0, stream>>>(xyz, xyz_fp, out_knn);
}